// Round 5
// baseline (185.739 us; speedup 1.0000x reference)
//
#include <hip/hip_runtime.h>

typedef unsigned short u16;
typedef __attribute__((ext_vector_type(8))) short short8;
typedef __attribute__((ext_vector_type(4))) float float4v;
typedef __attribute__((ext_vector_type(4))) unsigned short ushort4v;

__device__ __forceinline__ u16 f2bf(float f) {
    unsigned u = __float_as_uint(f);
    u += 0x7FFFu + ((u >> 16) & 1u);   // RNE
    return (u16)(u >> 16);
}
__device__ __forceinline__ float bf2f(u16 u) {
    return __uint_as_float(((unsigned)u) << 16);
}

// LDS-only barrier: drains ds ops (lgkm) but leaves global loads in flight.
// (__syncthreads drains vmcnt(0) too, which kills the B-stream prefetch.)
__device__ __forceinline__ void lds_barrier() {
    asm volatile("s_waitcnt lgkmcnt(0)\n\ts_barrier" ::: "memory");
}

// ---------------------------------------------------------------------------
// Module .bss intermediates (d_ws proved unreliable in earlier rounds).
// ---------------------------------------------------------------------------
__device__ float g_maxout[4 * 32 * 4096];   // 2 MB fp32
__device__ float g_q[16384];
__device__ float g_qmean[16384];
__device__ float g_lit[128];
__device__ float g_sigfac[16384];
__device__ u16   g_KwP[65536];              // K_w bf16, MFMA-fragment order
__device__ u16   g_KSAwP[16384];            // KSA_w bf16, MFMA-fragment order
__device__ u16   g_Kx[4 * 256 * 16384];     // Kx bf16, 33.5 MB

// Fragment order: each (o-tile, k-step) fragment = 1024 B contiguous,
// element (o,c) at frag*512 + (((c>>3)&3)*16 + (o&15))*8 + (c&7) shorts.
// K_w  [256 o][256 c]: frag = (o>>4)*8 + (c>>5)   (o-tile-major)
// KSA_w [32 o][512 c]: frag = (c>>5)*2 + (o>>4)   (k-step-major)
__global__ __launch_bounds__(256) void prep_kernel(
    const float* __restrict__ Kw, const float* __restrict__ KSAw)
{
    const int idx = blockIdx.x * 256 + threadIdx.x;
    if (idx < 128) g_lit[idx] = 0.f;
    if (idx < 65536) {
        const int o = idx >> 8, c = idx & 255;
        const int fi = ((o >> 4) << 3) + (c >> 5);
        const int ln = (((c >> 3) & 3) << 4) + (o & 15);
        g_KwP[fi * 512 + ln * 8 + (c & 7)] = f2bf(Kw[idx]);
    }
    if (idx < 16384) {
        const int o = idx >> 9, c = idx & 511;
        const int fi = ((c >> 5) << 1) + (o >> 4);
        const int ln = (((c >> 3) & 3) << 4) + (o & 15);
        g_KSAwP[fi * 512 + ln * 8 + (c & 7)] = f2bf(KSAw[idx]);
    }
}

// ---------------------------------------------------------------------------
// Deep conv via MFMA: maxout[b][o][p] = sum_c KSA_w[o][c]*deep[b][c][p]+bias
// M=32, K=512, N=4096/batch. Full A (32 KB, fragment order) staged to LDS
// ONCE -> barrier-free 16-step loop, conflict-free contiguous frag reads,
// distance-3 B register prefetch. qstats fused into the epilogue.
// ---------------------------------------------------------------------------
__global__ __launch_bounds__(256) void gemm_deep(
    const float* __restrict__ Bias, const float* __restrict__ X)
{
    __shared__ u16 As[16384];                 // [32 frag][512 shorts]
    const int t = threadIdx.x;
    const int wave = t >> 6, lane = t & 63;
    const int quad = lane >> 4, n16 = lane & 15;
    const int b = blockIdx.y;
    const int p = blockIdx.x * 64 + wave * 16 + n16;
    const float* Xb = X + ((long long)b << 21) + p;

    // Stage all of KSA_w (linear copy, conflict-free).
#pragma unroll
    for (int i = 0; i < 8; i++)
        *(short8*)(As + ((i << 8) + t) * 8) = *(const short8*)(g_KSAwP + ((i << 8) + t) * 8);

    float xr[3][8];
#define DXLOAD(dst, kb_) { \
    const float* xp_ = Xb + ((((kb_) << 5) + (quad << 3)) << 12); \
    _Pragma("unroll") for (int j = 0; j < 8; j++) dst[j] = xp_[j << 12]; }

    DXLOAD(xr[0], 0)
    DXLOAD(xr[1], 1)
    DXLOAD(xr[2], 2)

    __syncthreads();

    float4v acc[2];
#pragma unroll
    for (int i = 0; i < 2; i++) acc[i] = (float4v){0.f, 0.f, 0.f, 0.f};

#pragma unroll
    for (int kb = 0; kb < 16; kb++) {
        short8 bfrag;
#pragma unroll
        for (int j = 0; j < 8; j++) bfrag[j] = (short)f2bf(xr[kb % 3][j]);
        if (kb < 13) DXLOAD(xr[(kb + 3) % 3], kb + 3)
#pragma unroll
        for (int ot = 0; ot < 2; ot++) {
            const short8 afrag = *(const short8*)(As + (((kb << 1) + ot) << 9) + lane * 8);
            acc[ot] = __builtin_amdgcn_mfma_f32_16x16x32_bf16(afrag, bfrag, acc[ot], 0, 0, 0);
        }
    }
#undef DXLOAD

    // Epilogue: write maxout + fused qstats (channel max / mean per column).
    float mx = -3.4e38f, sm = 0.f;
#pragma unroll
    for (int ot = 0; ot < 2; ot++) {
#pragma unroll
        for (int r = 0; r < 4; r++) {
            const int o = ot * 16 + quad * 4 + r;
            const float v = acc[ot][r] + Bias[o];
            g_maxout[((b * 32 + o) << 12) + p] = v;
            mx = fmaxf(mx, v);
            sm += v;
        }
    }
    mx = fmaxf(mx, __shfl_xor(mx, 16, 64));
    sm += __shfl_xor(sm, 16, 64);
    mx = fmaxf(mx, __shfl_xor(mx, 32, 64));
    sm += __shfl_xor(sm, 32, 64);
    if (quad == 0) {
        g_q[(b << 12) + p] = mx;
        g_qmean[(b << 12) + p] = sm * (1.f / 32.f);
    }
}

// lit[b][l] = (1/4096) * sum_i q[b][i] * flat[b][i*32+l]
__global__ __launch_bounds__(256) void lit_kernel()
{
    const int b = blockIdx.y;
    const int f0 = blockIdx.x * 8192;
    const int t = threadIdx.x;
    const float* mo = g_maxout + (b << 17);
    const float* qb = g_q + (b << 12);
    float acc = 0.f;
#pragma unroll
    for (int it = 0; it < 32; it++) {
        const int f = f0 + it * 256 + t;
        acc += qb[f >> 5] * mo[f];
    }
    __shared__ float red[256];
    red[t] = acc;
    __syncthreads();
    if (t < 32) {
        float s = 0.f;
#pragma unroll
        for (int k = 0; k < 8; k++) s += red[t + k * 32];
        atomicAdd(&g_lit[b * 32 + t], s * (1.f / 4096.f));
    }
}

// re_score -> out tail (fp32); sigfac = 1 + sigmoid(re)
__global__ __launch_bounds__(256) void rescore_kernel(float* __restrict__ out_re)
{
    const int idx = blockIdx.x * 256 + threadIdx.x;  // 16384
    const int b = idx >> 12, p = idx & 4095;
    const float* mo = g_maxout + (b << 17) + p;
    const float* lb = g_lit + b * 32;
    float r = 0.f;
#pragma unroll
    for (int j = 0; j < 32; j++) r += lb[j] * mo[j << 12];
    out_re[idx] = r;
    g_sigfac[idx] = 1.f + 1.f / (1.f + __expf(-r));
}

// ---------------------------------------------------------------------------
// Shallow conv: Kx[b][o][p] = sum_c K_w[o][c]*shallow[b][c][p] + bias.
// v6: identical structure to v5 (frag-ordered LDS dbuf, lgkm-only barriers,
// distance-3 B stream) but __launch_bounds__(256,3): VGPR cap 170 so the
// ~130-reg live set (64 acc + 24 xr + 16 areg + addressing) fits WITHOUT
// scratch spill. R1-R4 all ran at VGPR=96 with ~7.5 MB/dispatch of spill
// writes in the K-loop (WRITE_SIZE 41 MB vs 33.5 logical) -- that spill,
// not LDS conflicts or barrier drains, was the 43 us floor.
// ---------------------------------------------------------------------------
__global__ __launch_bounds__(256, 3) void gemm_kx(
    const float* __restrict__ Bias, const float* __restrict__ X)
{
    __shared__ u16 As[2][8192];               // [buf][16 frag][512 shorts]
    const int t = threadIdx.x;
    const int wave = t >> 6, lane = t & 63;
    const int quad = lane >> 4, n16 = lane & 15;
    const int b = blockIdx.y;
    const int p0 = blockIdx.x * 64;
    const float* Xb = X + ((long long)b << 22) + p0 + wave * 16 + n16;

    // wave stages fragments ot = 4*wave .. 4*wave+3 for each k-step
    const u16* agbase = g_KwP + wave * 16384 + lane * 8;   // + i*4096 + kb*512
    const int alds = wave * 2048 + lane * 8;               // + i*512

    float xr[3][8];
#define XLOAD(dst, kb_) { \
    const float* xp_ = Xb + ((((kb_) << 5) + (quad << 3)) << 14); \
    _Pragma("unroll") for (int j = 0; j < 8; j++) dst[j] = xp_[j << 14]; }

    float4v acc[16];
#pragma unroll
    for (int i = 0; i < 16; i++) acc[i] = (float4v){0.f, 0.f, 0.f, 0.f};

    // prologue: A(0) global->reg->LDS buf0; B(0..2) in flight
    {
        short8 areg[4];
#pragma unroll
        for (int i = 0; i < 4; i++) areg[i] = *(const short8*)(agbase + i * 4096);
        XLOAD(xr[0], 0)
        XLOAD(xr[1], 1)
        XLOAD(xr[2], 2)
#pragma unroll
        for (int i = 0; i < 4; i++) *(short8*)(&As[0][alds + i * 512]) = areg[i];
    }
    lds_barrier();

#pragma unroll
    for (int kb = 0; kb < 8; kb++) {
        short8 areg[4];
        if (kb < 7) {                          // A(kb+1) global->reg (L2-hot)
#pragma unroll
            for (int i = 0; i < 4; i++)
                areg[i] = *(const short8*)(agbase + i * 4096 + (kb + 1) * 512);
        }
        short8 bfrag;
#pragma unroll
        for (int j = 0; j < 8; j++) bfrag[j] = (short)f2bf(xr[kb % 3][j]);
        if (kb < 5) XLOAD(xr[(kb + 3) % 3], kb + 3)   // B(kb+3) -> HBM stream

        const u16* ap = &As[kb & 1][lane * 8];
#pragma unroll
        for (int ot = 0; ot < 16; ot++) {
            const short8 afrag = *(const short8*)(ap + ot * 512);
            acc[ot] = __builtin_amdgcn_mfma_f32_16x16x32_bf16(
                bfrag, afrag, acc[ot], 0, 0, 0);
        }

        if (kb < 7) {                          // write-late into other buffer
#pragma unroll
            for (int i = 0; i < 4; i++)
                *(short8*)(&As[(kb + 1) & 1][alds + i * 512]) = areg[i];
            lds_barrier();
        }
    }
#undef XLOAD

    // D[p][o]: row(p) = quad*4+r, col(o) = ot*16+n16  (swapped operands)
    u16* kxb = g_Kx + (((long long)b << 8) << 14);
#pragma unroll
    for (int ot = 0; ot < 16; ot++) {
        const int o = ot * 16 + n16;
        const float bo = Bias[o];
        ushort4v w;
#pragma unroll
        for (int r = 0; r < 4; r++) w[r] = f2bf(acc[ot][r] + bo);
        *(ushort4v*)(kxb + ((long long)o << 14) + p0 + wave * 16 + (quad << 2)) = w;
    }
}

// ---------------------------------------------------------------------------
// Windowed softmax attention. Block = (b, 4-output-row strip, 8-o chunk):
// 2048 blocks, 2048 outputs each. qmean/sigfac read ONCE per thread into
// registers, reused across the 8 channels. Kx staged via packed uint loads
// into even/odd-split LDS planes (stride-2 window reads -> conflict-free).
// ---------------------------------------------------------------------------
__global__ __launch_bounds__(256) void att_window(float* __restrict__ out)
{
    __shared__ float tile[8][9][130];          // 37.4 KB
    const int t = threadIdx.x;
    const int o0 = blockIdx.y << 3, b = blockIdx.z;
    const int y0 = (blockIdx.x << 3) - 1;
    const u16* kxb = g_Kx + (((long long)b << 8) << 14);

    if (t < 72) tile[t / 9][t % 9][64] = 0.f;  // x=-1 pad per (o,row)
#pragma unroll
    for (int k = 0; k < 18; k++) {
        const int e = (k << 8) + t;            // 0..4607 = 72 rows x 64 pairs
        const int row = e >> 6, pr = e & 63;
        const int oi = row / 9, r = row - oi * 9;
        const int y = y0 + r;
        unsigned v = 0;
        if (y >= 0 && y < 128)
            v = *(const unsigned*)(kxb + (((long long)(o0 + oi)) << 14) + (y << 7) + (pr << 1));
        tile[oi][r][pr] = bf2f((u16)(v & 0xffffu));        // even x = 2*pr
        tile[oi][r][65 + pr] = bf2f((u16)(v >> 16));       // odd  x = 2*pr+1
    }
    __syncthreads();

    const int p = (blockIdx.x << 8) + t;       // 0..4095
    const int pw = t & 63;
    const int rl = (t >> 6) << 1;
    const float m = g_qmean[(b << 12) + p];
    const float sf = g_sigfac[(b << 12) + p];

#pragma unroll
    for (int oi = 0; oi < 8; oi++) {
        float v[9];
#pragma unroll
        for (int ki = 0; ki < 3; ++ki) {
            v[ki * 3 + 0] = tile[oi][rl + ki][64 + pw];    // x = 2pw-1
            v[ki * 3 + 1] = tile[oi][rl + ki][pw];         // x = 2pw
            v[ki * 3 + 2] = tile[oi][rl + ki][65 + pw];    // x = 2pw+1
        }
        float mx = -3.4e38f;
#pragma unroll
        for (int k = 0; k < 9; ++k) mx = fmaxf(mx, m * v[k]);
        float s = 0.f, a = 0.f;
#pragma unroll
        for (int k = 0; k < 9; ++k) {
            const float e = __expf(m * v[k] - mx);
            s += e;
            a += e * v[k];
        }
        out[((((long long)b << 8) + o0 + oi) << 12) + p] = (a / s) * sf;
    }
}

extern "C" void kernel_launch(void* const* d_in, const int* in_sizes, int n_in,
                              void* d_out, int out_size, void* d_ws, size_t ws_size,
                              hipStream_t stream) {
    const float *shallow = 0, *deep = 0, *K_w = 0, *K_b = 0, *KSA_w = 0, *KSA_b = 0;
    for (int i = 0; i < n_in; ++i) {
        switch (in_sizes[i]) {
            case 16777216: shallow = (const float*)d_in[i]; break;
            case 8388608:  deep    = (const float*)d_in[i]; break;
            case 65536:    K_w     = (const float*)d_in[i]; break;
            case 256:      K_b     = (const float*)d_in[i]; break;
            case 16384:    KSA_w   = (const float*)d_in[i]; break;
            case 32:       KSA_b   = (const float*)d_in[i]; break;
        }
    }
    float* out = (float*)d_out;   // FP32: 4194304 att + 16384 re_score

    // 0) zero lit + pack both weight matrices into MFMA-fragment order
    prep_kernel<<<320, 256, 0, stream>>>(K_w, KSA_w);
    // 1) deep conv (A in LDS once, barrier-free loop) + fused channel max/mean
    gemm_deep<<<dim3(64, 4), 256, 0, stream>>>(KSA_b, deep);
    // 2) lit (channel-scrambled, /hw)
    lit_kernel<<<dim3(16, 4), 256, 0, stream>>>();
    // 3) re_score (fp32 -> out tail) + sigmoid factor
    rescore_kernel<<<64, 256, 0, stream>>>(out + 4194304);
    // 4) shallow conv: frag-ordered LDS dbuf + lgkm-only barriers, no spill
    gemm_kx<<<dim3(256, 4), 256, 0, stream>>>(K_b, shallow);
    // 5) windowed softmax attention, 8 channels per block
    att_window<<<dim3(16, 32, 4), 256, 0, stream>>>(out);
}

// Round 6
// 181.590 us; speedup vs baseline: 1.0229x; 1.0229x over previous
//
#include <hip/hip_runtime.h>

typedef unsigned short u16;
typedef __attribute__((ext_vector_type(8))) short short8;
typedef __attribute__((ext_vector_type(4))) float float4v;
typedef __attribute__((ext_vector_type(4))) unsigned short ushort4v;

__device__ __forceinline__ u16 f2bf(float f) {
    unsigned u = __float_as_uint(f);
    u += 0x7FFFu + ((u >> 16) & 1u);   // RNE
    return (u16)(u >> 16);
}
__device__ __forceinline__ float bf2f(u16 u) {
    return __uint_as_float(((unsigned)u) << 16);
}

// LDS-only barrier: drains ds ops (lgkm) but leaves global loads in flight.
__device__ __forceinline__ void lds_barrier() {
    asm volatile("s_waitcnt lgkmcnt(0)\n\ts_barrier" ::: "memory");
}

// ---------------------------------------------------------------------------
// Module .bss intermediates (d_ws proved unreliable in earlier rounds).
// ---------------------------------------------------------------------------
__device__ float g_maxout[4 * 32 * 4096];   // 2 MB fp32, o-major (for lit)
__device__ float g_maxoutT[4 * 4096 * 32];  // 2 MB fp32, p-major (for rescore)
__device__ float g_q[16384];
__device__ float g_qmean[16384];
__device__ float g_lit[128];
__device__ float g_sigfac[16384];
__device__ u16   g_KwP[65536];              // K_w bf16, MFMA-fragment order
__device__ u16   g_KSAwP[16384];            // KSA_w bf16, MFMA-fragment order
__device__ u16   g_Kx[4 * 256 * 16384];     // Kx bf16, 33.5 MB

// Fragment order: each (o-tile, k-step) fragment = 1024 B contiguous,
// element (o,c) at frag*512 + (((c>>3)&3)*16 + (o&15))*8 + (c&7) shorts.
// K_w  [256 o][256 c]: frag = (o>>4)*8 + (c>>5)   (o-tile-major)
// KSA_w [32 o][512 c]: frag = (c>>5)*2 + (o>>4)   (k-step-major)
__global__ __launch_bounds__(256) void prep_kernel(
    const float* __restrict__ Kw, const float* __restrict__ KSAw)
{
    const int idx = blockIdx.x * 256 + threadIdx.x;
    if (idx < 128) g_lit[idx] = 0.f;
    if (idx < 65536) {
        const int o = idx >> 8, c = idx & 255;
        const int fi = ((o >> 4) << 3) + (c >> 5);
        const int ln = (((c >> 3) & 3) << 4) + (o & 15);
        g_KwP[fi * 512 + ln * 8 + (c & 7)] = f2bf(Kw[idx]);
    }
    if (idx < 16384) {
        const int o = idx >> 9, c = idx & 511;
        const int fi = ((c >> 5) << 1) + (o >> 4);
        const int ln = (((c >> 3) & 3) << 4) + (o & 15);
        g_KSAwP[fi * 512 + ln * 8 + (c & 7)] = f2bf(KSAw[idx]);
    }
}

// ---------------------------------------------------------------------------
// Deep conv via MFMA: maxout[b][o][p] = sum_c KSA_w[o][c]*deep[b][c][p]+bias
// M=32, K=512, N=4096/batch. Full A (32 KB, fragment order) staged to LDS
// ONCE -> barrier-free 16-step loop, conflict-free contiguous frag reads,
// distance-3 B register prefetch. qstats fused; dual maxout/maxoutT write.
// ---------------------------------------------------------------------------
__global__ __launch_bounds__(256) void gemm_deep(
    const float* __restrict__ Bias, const float* __restrict__ X)
{
    __shared__ u16 As[16384];                 // [32 frag][512 shorts]
    const int t = threadIdx.x;
    const int wave = t >> 6, lane = t & 63;
    const int quad = lane >> 4, n16 = lane & 15;
    const int b = blockIdx.y;
    const int p = blockIdx.x * 64 + wave * 16 + n16;
    const float* Xb = X + ((long long)b << 21) + p;

    // Stage all of KSA_w (linear copy, conflict-free).
#pragma unroll
    for (int i = 0; i < 8; i++)
        *(short8*)(As + ((i << 8) + t) * 8) = *(const short8*)(g_KSAwP + ((i << 8) + t) * 8);

    float xr[3][8];
#define DXLOAD(dst, kb_) { \
    const float* xp_ = Xb + ((((kb_) << 5) + (quad << 3)) << 12); \
    _Pragma("unroll") for (int j = 0; j < 8; j++) dst[j] = xp_[j << 12]; }

    DXLOAD(xr[0], 0)
    DXLOAD(xr[1], 1)
    DXLOAD(xr[2], 2)

    __syncthreads();

    float4v acc[2];
#pragma unroll
    for (int i = 0; i < 2; i++) acc[i] = (float4v){0.f, 0.f, 0.f, 0.f};

#pragma unroll
    for (int kb = 0; kb < 16; kb++) {
        short8 bfrag;
#pragma unroll
        for (int j = 0; j < 8; j++) bfrag[j] = (short)f2bf(xr[kb % 3][j]);
        if (kb < 13) DXLOAD(xr[(kb + 3) % 3], kb + 3)
#pragma unroll
        for (int ot = 0; ot < 2; ot++) {
            const short8 afrag = *(const short8*)(As + (((kb << 1) + ot) << 9) + lane * 8);
            acc[ot] = __builtin_amdgcn_mfma_f32_16x16x32_bf16(afrag, bfrag, acc[ot], 0, 0, 0);
        }
    }
#undef DXLOAD

    // Epilogue: maxout (o-major) + maxoutT (p-major, float4) + fused qstats.
    float mx = -3.4e38f, sm = 0.f;
#pragma unroll
    for (int ot = 0; ot < 2; ot++) {
        float4v vv;
#pragma unroll
        for (int r = 0; r < 4; r++) {
            const int o = ot * 16 + quad * 4 + r;
            vv[r] = acc[ot][r] + Bias[o];
            g_maxout[((b * 32 + o) << 12) + p] = vv[r];
            mx = fmaxf(mx, vv[r]);
            sm += vv[r];
        }
        *(float4v*)(g_maxoutT + (((b << 12) + p) << 5) + ot * 16 + quad * 4) = vv;
    }
    mx = fmaxf(mx, __shfl_xor(mx, 16, 64));
    sm += __shfl_xor(sm, 16, 64);
    mx = fmaxf(mx, __shfl_xor(mx, 32, 64));
    sm += __shfl_xor(sm, 32, 64);
    if (quad == 0) {
        g_q[(b << 12) + p] = mx;
        g_qmean[(b << 12) + p] = sm * (1.f / 32.f);
    }
}

// lit[b][l] = (1/4096) * sum_i q[b][i] * flat[b][i*32+l]; 512 blocks (2/CU).
__global__ __launch_bounds__(256) void lit_kernel()
{
    const int b = blockIdx.y;
    const int f0 = blockIdx.x * 1024;
    const int t = threadIdx.x;
    const float* mo = g_maxout + (b << 17);
    const float* qb = g_q + (b << 12);
    float acc = 0.f;
#pragma unroll
    for (int it = 0; it < 4; it++) {
        const int f = f0 + it * 256 + t;
        acc += qb[f >> 5] * mo[f];
    }
    __shared__ float red[256];
    red[t] = acc;
    __syncthreads();
    if (t < 32) {
        float s = 0.f;
#pragma unroll
        for (int k = 0; k < 8; k++) s += red[t + k * 32];
        atomicAdd(&g_lit[b * 32 + t], s * (1.f / 4096.f));
    }
}

// re_score -> out tail (fp32); sigfac = 1 + sigmoid(re).
// Reads p-major maxoutT: 8 contiguous float4 per thread (fully coalesced).
__global__ __launch_bounds__(128) void rescore_kernel(float* __restrict__ out_re)
{
    const int idx = blockIdx.x * 128 + threadIdx.x;  // 16384
    const int b = idx >> 12;
    const float4v* mt = (const float4v*)(g_maxoutT + (idx << 5));
    const float4v* lb = (const float4v*)(g_lit + b * 32);
    float r = 0.f;
#pragma unroll
    for (int j = 0; j < 8; j++) {
        const float4v m4 = mt[j];
        const float4v l4 = lb[j];
        r += m4[0] * l4[0] + m4[1] * l4[1] + m4[2] * l4[2] + m4[3] * l4[3];
    }
    out_re[idx] = r;
    g_sigfac[idx] = 1.f + 1.f / (1.f + __expf(-r));
}

// ---------------------------------------------------------------------------
// Shallow conv: Kx[b][o][p] = sum_c K_w[o][c]*shallow[b][c][p] + bias.
// R4-identical (best measured variant, 43.5 us): frag-ordered LDS dbuf,
// lgkm-only barriers, distance-3 B stream, swapped-operand MFMA.
// ---------------------------------------------------------------------------
__global__ __launch_bounds__(256) void gemm_kx(
    const float* __restrict__ Bias, const float* __restrict__ X)
{
    __shared__ u16 As[2][8192];               // [buf][16 frag][512 shorts]
    const int t = threadIdx.x;
    const int wave = t >> 6, lane = t & 63;
    const int quad = lane >> 4, n16 = lane & 15;
    const int b = blockIdx.y;
    const int p0 = blockIdx.x * 64;
    const float* Xb = X + ((long long)b << 22) + p0 + wave * 16 + n16;

    const u16* agbase = g_KwP + wave * 16384 + lane * 8;   // + i*4096 + kb*512
    const int alds = wave * 2048 + lane * 8;               // + i*512

    float xr[3][8];
#define XLOAD(dst, kb_) { \
    const float* xp_ = Xb + ((((kb_) << 5) + (quad << 3)) << 14); \
    _Pragma("unroll") for (int j = 0; j < 8; j++) dst[j] = xp_[j << 14]; }

    float4v acc[16];
#pragma unroll
    for (int i = 0; i < 16; i++) acc[i] = (float4v){0.f, 0.f, 0.f, 0.f};

    // prologue: A(0) global->reg->LDS buf0; B(0..2) in flight
    {
        short8 areg[4];
#pragma unroll
        for (int i = 0; i < 4; i++) areg[i] = *(const short8*)(agbase + i * 4096);
        XLOAD(xr[0], 0)
        XLOAD(xr[1], 1)
        XLOAD(xr[2], 2)
#pragma unroll
        for (int i = 0; i < 4; i++) *(short8*)(&As[0][alds + i * 512]) = areg[i];
    }
    lds_barrier();

#pragma unroll
    for (int kb = 0; kb < 8; kb++) {
        short8 areg[4];
        if (kb < 7) {                          // A(kb+1) global->reg (L2-hot)
#pragma unroll
            for (int i = 0; i < 4; i++)
                areg[i] = *(const short8*)(agbase + i * 4096 + (kb + 1) * 512);
        }
        short8 bfrag;
#pragma unroll
        for (int j = 0; j < 8; j++) bfrag[j] = (short)f2bf(xr[kb % 3][j]);
        if (kb < 5) XLOAD(xr[(kb + 3) % 3], kb + 3)   // B(kb+3) -> HBM stream

        const u16* ap = &As[kb & 1][lane * 8];
#pragma unroll
        for (int ot = 0; ot < 16; ot++) {
            const short8 afrag = *(const short8*)(ap + ot * 512);
            acc[ot] = __builtin_amdgcn_mfma_f32_16x16x32_bf16(
                bfrag, afrag, acc[ot], 0, 0, 0);
        }

        if (kb < 7) {                          // write-late into other buffer
#pragma unroll
            for (int i = 0; i < 4; i++)
                *(short8*)(&As[(kb + 1) & 1][alds + i * 512]) = areg[i];
            lds_barrier();
        }
    }
#undef XLOAD

    // D[p][o]: row(p) = quad*4+r, col(o) = ot*16+n16  (swapped operands)
    u16* kxb = g_Kx + (((long long)b << 8) << 14);
#pragma unroll
    for (int ot = 0; ot < 16; ot++) {
        const int o = ot * 16 + n16;
        const float bo = Bias[o];
        ushort4v w;
#pragma unroll
        for (int r = 0; r < 4; r++) w[r] = f2bf(acc[ot][r] + bo);
        *(ushort4v*)(kxb + ((long long)o << 14) + p0 + wave * 16 + (quad << 2)) = w;
    }
}

// ---------------------------------------------------------------------------
// Windowed softmax attention. Block = (b, 4-output-row strip, 8-o chunk).
// v7: bf16 LDS tile (18.6 KB vs 37.4) -> 8 blocks/CU. u16 even/odd planes,
// consecutive-lane u16 access = 2-way conflict (free). qmean/sigfac in regs.
// ---------------------------------------------------------------------------
__global__ __launch_bounds__(256) void att_window(float* __restrict__ out)
{
    __shared__ u16 tile[8][9][132];            // 18.6 KB
    const int t = threadIdx.x;
    const int o0 = blockIdx.y << 3, b = blockIdx.z;
    const int y0 = (blockIdx.x << 3) - 1;
    const u16* kxb = g_Kx + (((long long)b << 8) << 14);

    if (t < 72) tile[t / 9][t % 9][64] = 0;    // x=-1 pad per (o,row)
#pragma unroll
    for (int k = 0; k < 18; k++) {
        const int e = (k << 8) + t;            // 0..4607 = 72 rows x 64 pairs
        const int row = e >> 6, pr = e & 63;
        const int oi = row / 9, r = row - oi * 9;
        const int y = y0 + r;
        unsigned v = 0;
        if (y >= 0 && y < 128)
            v = *(const unsigned*)(kxb + (((long long)(o0 + oi)) << 14) + (y << 7) + (pr << 1));
        tile[oi][r][pr] = (u16)(v & 0xffffu);          // even x = 2*pr
        tile[oi][r][65 + pr] = (u16)(v >> 16);         // odd  x = 2*pr+1
    }
    __syncthreads();

    const int p = (blockIdx.x << 8) + t;       // 0..4095
    const int pw = t & 63;
    const int rl = (t >> 6) << 1;
    const float m = g_qmean[(b << 12) + p];
    const float sf = g_sigfac[(b << 12) + p];

#pragma unroll
    for (int oi = 0; oi < 8; oi++) {
        float v[9];
#pragma unroll
        for (int ki = 0; ki < 3; ++ki) {
            v[ki * 3 + 0] = bf2f(tile[oi][rl + ki][64 + pw]);   // x = 2pw-1
            v[ki * 3 + 1] = bf2f(tile[oi][rl + ki][pw]);        // x = 2pw
            v[ki * 3 + 2] = bf2f(tile[oi][rl + ki][65 + pw]);   // x = 2pw+1
        }
        float mx = -3.4e38f;
#pragma unroll
        for (int k = 0; k < 9; ++k) mx = fmaxf(mx, m * v[k]);
        float s = 0.f, a = 0.f;
#pragma unroll
        for (int k = 0; k < 9; ++k) {
            const float e = __expf(m * v[k] - mx);
            s += e;
            a += e * v[k];
        }
        out[((((long long)b << 8) + o0 + oi) << 12) + p] = (a / s) * sf;
    }
}

extern "C" void kernel_launch(void* const* d_in, const int* in_sizes, int n_in,
                              void* d_out, int out_size, void* d_ws, size_t ws_size,
                              hipStream_t stream) {
    const float *shallow = 0, *deep = 0, *K_w = 0, *K_b = 0, *KSA_w = 0, *KSA_b = 0;
    for (int i = 0; i < n_in; ++i) {
        switch (in_sizes[i]) {
            case 16777216: shallow = (const float*)d_in[i]; break;
            case 8388608:  deep    = (const float*)d_in[i]; break;
            case 65536:    K_w     = (const float*)d_in[i]; break;
            case 256:      K_b     = (const float*)d_in[i]; break;
            case 16384:    KSA_w   = (const float*)d_in[i]; break;
            case 32:       KSA_b   = (const float*)d_in[i]; break;
        }
    }
    float* out = (float*)d_out;   // FP32: 4194304 att + 16384 re_score

    // 0) zero lit + pack both weight matrices into MFMA-fragment order
    prep_kernel<<<320, 256, 0, stream>>>(K_w, KSA_w);
    // 1) deep conv + fused channel max/mean + transposed maxout
    gemm_deep<<<dim3(64, 4), 256, 0, stream>>>(KSA_b, deep);
    // 2) lit (channel-scrambled, /hw), 512 blocks
    lit_kernel<<<dim3(128, 4), 256, 0, stream>>>();
    // 3) re_score (fp32 -> out tail) + sigmoid factor, coalesced maxoutT reads
    rescore_kernel<<<128, 128, 0, stream>>>(out + 4194304);
    // 4) shallow conv (R4-identical best variant) -> Kx bf16
    gemm_kx<<<dim3(256, 4), 256, 0, stream>>>(K_b, shallow);
    // 5) windowed softmax attention, 8 channels per block, bf16 LDS tile
    att_window<<<dim3(16, 32, 4), 256, 0, stream>>>(out);
}